// Round 1
// baseline (121.133 us; speedup 1.0000x reference)
//
#include <hip/hip_runtime.h>

// pos/seq_lens fill for ragged batch metadata.
// d_out layout (int32): [0, num_tokens) = pos, [num_tokens, +max_num_reqs) = seq_lens.
//
// R6 = R5 with the hot kernel restructured from 1 tile/block to 8 tiles/block.
// R5 post-mortem: pos_kernel ran at ~1.7 TB/s while the harness fill hits
// 6.4 TB/s on the same buffer -> the store pipe is NOT the limit. Each R5
// block had a ~500+ cycle dependent scalar-load chain (tile_req -> base_req)
// amortized over ONE 16B store per thread (4 KiB/block) -> block-turnover /
// latency bound. Fix: CHUNK=8 tiles per block, all 9 tile_req boundaries and
// 8 base_req values prefetched up-front (independent loads, latency
// overlapped), 8 pipelined nontemporal wave-stores per wave. 2048 blocks =
// 8 blocks/CU x 4 waves = full 32-wave occupancy.

#define TPB 256
#define TILE_TOK 1024                       // tokens per tile (1 int4/thread)
#define CHUNK 8                             // tiles per block in hot kernel
#define SEQ_PER_BLOCK (TPB * 4)             // 1024

typedef int vint4 __attribute__((ext_vector_type(4)));

// ---------- prep: base_req + tile_req + seq_lens ----------
__global__ __launch_bounds__(TPB) void prep_kernel(
    const int* __restrict__ idx_mapping,
    const int* __restrict__ qsl,          // [num_reqs+1]
    const int* __restrict__ nct,          // [max_num_reqs]
    int* __restrict__ tile_req,           // [num_tiles+1]   (d_ws)
    int* __restrict__ base_req,           // [num_reqs]      (d_ws)
    int* __restrict__ seq_out,            // [max_num_reqs]
    int num_reqs, int max_num_reqs, int num_tokens,
    int bound_count, int bound_blocks)
{
    int b = blockIdx.x;
    if (b < bound_blocks) {
        int j = b * TPB + (int)threadIdx.x;
        if (j >= bound_count) return;
        long long tl = (long long)j * TILE_TOK;
        int t = (tl >= num_tokens) ? (num_tokens - 1) : (int)tl;
        // last r in [0, num_reqs] with qsl[r] <= t  (== searchsorted-right - 1)
        int l = 0, h = num_reqs + 1;
        while (h - l > 1) {
            int mid = (l + h) >> 1;
            if (qsl[mid] <= t) l = mid; else h = mid;
        }
        tile_req[j] = l;
        return;
    }
    // ---- base_req + seq_lens ----
    int i = (b - bound_blocks) * SEQ_PER_BLOCK + (int)threadIdx.x * 4;
    if (i >= max_num_reqs) return;
    vint4 v;
    #pragma unroll
    for (int k = 0; k < 4; ++k) {
        int idx = i + k;
        int val = 0;
        if (idx < num_reqs) {
            int q0 = qsl[idx], q1 = qsl[idx + 1];
            int nb = nct[idx_mapping[idx]];
            base_req[idx] = nb - q0;
            val = nb + (q1 - q0);
        }
        v[k] = val;
    }
    if (i + 4 <= max_num_reqs) {
        *(vint4*)(seq_out + i) = v;
    } else {
        for (int k = 0; k < max_num_reqs - i; ++k) seq_out[i + k] = v[k];
    }
}

// ---------- hot: pos fill, CHUNK tiles per block ----------
__global__ __launch_bounds__(TPB) void pos_kernel(
    const int* __restrict__ qsl,          // [num_reqs+1]
    const int* __restrict__ tile_req,     // [num_tiles+1]
    const int* __restrict__ base_req,     // [num_reqs]
    int* __restrict__ pos_out,            // [num_tokens]
    int num_tokens, int num_tiles)
{
    const int tile0 = (int)blockIdx.x * CHUNK;

    // Prefetch all tile boundaries for this chunk (uniform -> scalar loads,
    // all independent, issued back-to-back so latency overlaps).
    int tr[CHUNK + 1];
    #pragma unroll
    for (int i = 0; i <= CHUNK; ++i) {
        int tl = tile0 + i;
        tr[i] = tile_req[(tl <= num_tiles) ? tl : num_tiles];
    }
    // Prefetch base_req for each tile's first request (also uniform).
    int bs[CHUNK];
    #pragma unroll
    for (int i = 0; i < CHUNK; ++i) {
        bs[i] = base_req[tr[i]];
    }

    #pragma unroll
    for (int i = 0; i < CHUNK; ++i) {
        int tile = tile0 + i;
        int t = tile * TILE_TOK + (int)threadIdx.x * 4;
        if (t >= num_tokens) break;

        int r0 = tr[i];                   // wave-uniform
        int r1 = tr[i + 1];
        vint4 v;

        if (r0 == r1) {
            // whole tile inside one request: pure stream
            int base = bs[i];
            v[0] = t + base; v[1] = t + 1 + base;
            v[2] = t + 2 + base; v[3] = t + 3 + base;
        } else {
            int r = r0;
            int base = bs[i];
            int next = qsl[r + 1];
            while (next <= t) {           // advance to this thread's request
                ++r;
                next = qsl[r + 1];
                base = base_req[r];
            }
            #pragma unroll
            for (int k = 0; k < 4; ++k) {
                int tk = t + k;
                while (tk >= next) {      // handles empty requests too
                    ++r;
                    next = qsl[r + 1];
                    base = base_req[r];
                }
                v[k] = base + tk;
            }
        }

        if (t + 4 <= num_tokens) {
            __builtin_nontemporal_store(v, (vint4*)(pos_out + t));
        } else {
            for (int k = 0; k < num_tokens - t; ++k) pos_out[t + k] = v[k];
        }
    }
}

extern "C" void kernel_launch(void* const* d_in, const int* in_sizes, int n_in,
                              void* d_out, int out_size, void* d_ws, size_t ws_size,
                              hipStream_t stream) {
    const int* idx_mapping = (const int*)d_in[0];
    const int* qsl         = (const int*)d_in[1];
    const int* nct         = (const int*)d_in[2];
    // d_in[3] (pos buffer) and d_in[4] (seq_lens buffer) are unused inputs.

    int num_reqs     = in_sizes[0];
    int max_num_reqs = in_sizes[2];
    int num_tokens   = in_sizes[3];

    int* out = (int*)d_out;
    int* pos_out = out;
    int* seq_out = out + num_tokens;

    int num_tiles   = (int)(((long long)num_tokens + TILE_TOK - 1) / TILE_TOK); // 16384
    int bound_count = num_tiles + 1;                                            // 16385
    int* tile_req = (int*)d_ws;
    int* base_req = tile_req + (bound_count + 3) / 4 * 4;

    int bound_blocks = (bound_count + TPB - 1) / TPB;                           // 65
    int seq_blocks   = (max_num_reqs + SEQ_PER_BLOCK - 1) / SEQ_PER_BLOCK;      // 16
    int hot_blocks   = (num_tiles + CHUNK - 1) / CHUNK;                         // 2048

    prep_kernel<<<dim3(bound_blocks + seq_blocks), dim3(TPB), 0, stream>>>(
        idx_mapping, qsl, nct, tile_req, base_req, seq_out,
        num_reqs, max_num_reqs, num_tokens, bound_count, bound_blocks);

    pos_kernel<<<dim3(hot_blocks), dim3(TPB), 0, stream>>>(
        qsl, tile_req, base_req, pos_out, num_tokens, num_tiles);
}

// Round 2
// 119.535 us; speedup vs baseline: 1.0134x; 1.0134x over previous
//
#include <hip/hip_runtime.h>

// pos/seq_lens fill for ragged batch metadata.
// d_out layout (int32): [0, num_tokens) = pos, [num_tokens, +max_num_reqs) = seq_lens.
//
// R7 = R6 with ONE change: nontemporal stores -> plain stores.
// R6 post-mortem: CHUNK=8 restructure (latency-turnover fix) was a null
// delta (120.1 -> 121.1 us), so per-block latency was NOT the binding
// constraint. Remaining discriminating theory: every version since R3 used
// __builtin_nontemporal_store (L2-bypass) and all measured ~1.5 TB/s on the
// pos stream, while the harness fillBufferAligned hits 6.5 TB/s on the SAME
// buffer with regular stores (FETCH_SIZE ~ 0 -> full-line writes, no RFO).
// If the nt path is the ~1.5 TB/s wall, plain stores drop pos ~45 -> ~12 us.
// If total stays ~120, the timed region is harness-fill-dominated and we
// are at the controllable floor (declare roofline).

#define TPB 256
#define TILE_TOK 1024                       // tokens per tile (1 int4/thread)
#define CHUNK 8                             // tiles per block in hot kernel
#define SEQ_PER_BLOCK (TPB * 4)             // 1024

typedef int vint4 __attribute__((ext_vector_type(4)));

// ---------- prep: base_req + tile_req + seq_lens ----------
__global__ __launch_bounds__(TPB) void prep_kernel(
    const int* __restrict__ idx_mapping,
    const int* __restrict__ qsl,          // [num_reqs+1]
    const int* __restrict__ nct,          // [max_num_reqs]
    int* __restrict__ tile_req,           // [num_tiles+1]   (d_ws)
    int* __restrict__ base_req,           // [num_reqs]      (d_ws)
    int* __restrict__ seq_out,            // [max_num_reqs]
    int num_reqs, int max_num_reqs, int num_tokens,
    int bound_count, int bound_blocks)
{
    int b = blockIdx.x;
    if (b < bound_blocks) {
        int j = b * TPB + (int)threadIdx.x;
        if (j >= bound_count) return;
        long long tl = (long long)j * TILE_TOK;
        int t = (tl >= num_tokens) ? (num_tokens - 1) : (int)tl;
        // last r in [0, num_reqs] with qsl[r] <= t  (== searchsorted-right - 1)
        int l = 0, h = num_reqs + 1;
        while (h - l > 1) {
            int mid = (l + h) >> 1;
            if (qsl[mid] <= t) l = mid; else h = mid;
        }
        tile_req[j] = l;
        return;
    }
    // ---- base_req + seq_lens ----
    int i = (b - bound_blocks) * SEQ_PER_BLOCK + (int)threadIdx.x * 4;
    if (i >= max_num_reqs) return;
    vint4 v;
    #pragma unroll
    for (int k = 0; k < 4; ++k) {
        int idx = i + k;
        int val = 0;
        if (idx < num_reqs) {
            int q0 = qsl[idx], q1 = qsl[idx + 1];
            int nb = nct[idx_mapping[idx]];
            base_req[idx] = nb - q0;
            val = nb + (q1 - q0);
        }
        v[k] = val;
    }
    if (i + 4 <= max_num_reqs) {
        *(vint4*)(seq_out + i) = v;
    } else {
        for (int k = 0; k < max_num_reqs - i; ++k) seq_out[i + k] = v[k];
    }
}

// ---------- hot: pos fill, CHUNK tiles per block ----------
__global__ __launch_bounds__(TPB) void pos_kernel(
    const int* __restrict__ qsl,          // [num_reqs+1]
    const int* __restrict__ tile_req,     // [num_tiles+1]
    const int* __restrict__ base_req,     // [num_reqs]
    int* __restrict__ pos_out,            // [num_tokens]
    int num_tokens, int num_tiles)
{
    const int tile0 = (int)blockIdx.x * CHUNK;

    // Prefetch all tile boundaries for this chunk (uniform -> scalar loads,
    // all independent, issued back-to-back so latency overlaps).
    int tr[CHUNK + 1];
    #pragma unroll
    for (int i = 0; i <= CHUNK; ++i) {
        int tl = tile0 + i;
        tr[i] = tile_req[(tl <= num_tiles) ? tl : num_tiles];
    }
    // Prefetch base_req for each tile's first request (also uniform).
    int bs[CHUNK];
    #pragma unroll
    for (int i = 0; i < CHUNK; ++i) {
        bs[i] = base_req[tr[i]];
    }

    #pragma unroll
    for (int i = 0; i < CHUNK; ++i) {
        int tile = tile0 + i;
        int t = tile * TILE_TOK + (int)threadIdx.x * 4;
        if (t >= num_tokens) break;

        int r0 = tr[i];                   // wave-uniform
        int r1 = tr[i + 1];
        vint4 v;

        if (r0 == r1) {
            // whole tile inside one request: pure stream
            int base = bs[i];
            v[0] = t + base; v[1] = t + 1 + base;
            v[2] = t + 2 + base; v[3] = t + 3 + base;
        } else {
            int r = r0;
            int base = bs[i];
            int next = qsl[r + 1];
            while (next <= t) {           // advance to this thread's request
                ++r;
                next = qsl[r + 1];
                base = base_req[r];
            }
            #pragma unroll
            for (int k = 0; k < 4; ++k) {
                int tk = t + k;
                while (tk >= next) {      // handles empty requests too
                    ++r;
                    next = qsl[r + 1];
                    base = base_req[r];
                }
                v[k] = base + tk;
            }
        }

        if (t + 4 <= num_tokens) {
            *(vint4*)(pos_out + t) = v;   // plain store (through L2), like the fill
        } else {
            for (int k = 0; k < num_tokens - t; ++k) pos_out[t + k] = v[k];
        }
    }
}

extern "C" void kernel_launch(void* const* d_in, const int* in_sizes, int n_in,
                              void* d_out, int out_size, void* d_ws, size_t ws_size,
                              hipStream_t stream) {
    const int* idx_mapping = (const int*)d_in[0];
    const int* qsl         = (const int*)d_in[1];
    const int* nct         = (const int*)d_in[2];
    // d_in[3] (pos buffer) and d_in[4] (seq_lens buffer) are unused inputs.

    int num_reqs     = in_sizes[0];
    int max_num_reqs = in_sizes[2];
    int num_tokens   = in_sizes[3];

    int* out = (int*)d_out;
    int* pos_out = out;
    int* seq_out = out + num_tokens;

    int num_tiles   = (int)(((long long)num_tokens + TILE_TOK - 1) / TILE_TOK); // 16384
    int bound_count = num_tiles + 1;                                            // 16385
    int* tile_req = (int*)d_ws;
    int* base_req = tile_req + (bound_count + 3) / 4 * 4;

    int bound_blocks = (bound_count + TPB - 1) / TPB;                           // 65
    int seq_blocks   = (max_num_reqs + SEQ_PER_BLOCK - 1) / SEQ_PER_BLOCK;      // 16
    int hot_blocks   = (num_tiles + CHUNK - 1) / CHUNK;                         // 2048

    prep_kernel<<<dim3(bound_blocks + seq_blocks), dim3(TPB), 0, stream>>>(
        idx_mapping, qsl, nct, tile_req, base_req, seq_out,
        num_reqs, max_num_reqs, num_tokens, bound_count, bound_blocks);

    pos_kernel<<<dim3(hot_blocks), dim3(TPB), 0, stream>>>(
        qsl, tile_req, base_req, pos_out, num_tokens, num_tiles);
}